// Round 14
// baseline (307.234 us; speedup 1.0000x reference)
//
#include <hip/hip_runtime.h>
#include <hip/hip_bf16.h>

typedef __attribute__((ext_vector_type(8))) __bf16 bf16x8;
typedef __attribute__((ext_vector_type(4))) float f32x4;

#define NN 20000
#define GRID1 512    // 256-thread blocks, 2 blocks/CU (VGPR-limited: ~212 regs/thread)
#define NSLOT 512    // node stride

// Pack W1 (64x128 f32, row-major) -> w1p[c][k] bf16 (c<128, k<64)
// Pack W2 (128x64 f32, row-major) -> w2p[c][k] bf16 (c<64, k<128)
__global__ void pack_w(const float* __restrict__ W1, const float* __restrict__ W2,
                       __bf16* __restrict__ w1p, __bf16* __restrict__ w2p) {
    int i = blockIdx.x * 256 + threadIdx.x;   // grid 32 * 256 = 8192
    if (i < 64 * 128) {
        int c = i >> 6, k = i & 63;
        w1p[i] = (__bf16)W1[k * 128 + c];
        int c2 = i >> 7, k2 = i & 127;
        w2p[i] = (__bf16)W2[k2 * 64 + c2];
    }
}

struct NodeBuf { float4 sx[4]; int4 mv[4]; int gi; int rv; };

// ---------------- Stage 1 (persistent, 256 threads = 4 waves = 1 node-slot) ----------------
// ALL weights live in VGPRs (128 regs of bf16x8 fragments, loaded once) -> LDS carries only the
// per-wave h round-trip (8 KB/wave-iter vs 40 before); fc1 is a pure-register MFMA burst.
// Zero barriers. rv-predicated loads + rv/gi one iteration ahead (R12/R13 pipeline).
__global__ __launch_bounds__(256, 2) void vpsl_stage1p(
    const float* __restrict__ S, const int* __restrict__ mask,
    const int* __restrict__ gidx, const int* __restrict__ rvalid,
    const __bf16* __restrict__ w1p, const __bf16* __restrict__ w2p,
    const float* __restrict__ b1, const float* __restrict__ b2,
    float* __restrict__ midg)
{
    __shared__ __align__(16) __bf16 h_lds[4][16][136];   // per-wave h tile, pitch 136, 17 KB

    const int tid  = threadIdx.x;
    const int w    = tid >> 6;     // wave 0..3 -> rows 16w..16w+15
    const int lane = tid & 63;
    const int g    = lane >> 4;    // 16-lane group
    const int lc   = lane & 15;

    // ---- weights -> registers, once (loop-invariant; all indices compile-time) ----
    bf16x8 w1f[16];   // w1f[t*2+ks] = W1[k=ks*32+g*8 .. +8][c=t*16+lc]
#pragma unroll
    for (int t = 0; t < 8; ++t)
#pragma unroll
        for (int ks = 0; ks < 2; ++ks)
            w1f[t * 2 + ks] = *reinterpret_cast<const bf16x8*>(w1p + (t * 16 + lc) * 64 + ks * 32 + g * 8);
    bf16x8 w2f[16];   // w2f[ks*4+tm] = W2[k=ks*32+g*8 .. +8][c=tm*16+lc]
#pragma unroll
    for (int ks = 0; ks < 4; ++ks)
#pragma unroll
        for (int tm = 0; tm < 4; ++tm)
            w2f[ks * 4 + tm] = *reinterpret_cast<const bf16x8*>(w2p + (tm * 16 + lc) * 128 + ks * 32 + g * 8);

    // biases (uniform, L1-hot); folded into accumulator inits
    float b1v[8];
#pragma unroll
    for (int t = 0; t < 8; ++t) b1v[t] = b1[t * 16 + lc];
    float4 b2v4[4];
#pragma unroll
    for (int tm = 0; tm < 4; ++tm) b2v4[tm] = *reinterpret_cast<const float4*>(b2 + 16 * tm + 4 * g);

    const int r = 16 * w + lc;   // this lane's softmax row

    auto LOADRV = [&](int2& rg, int node) {
        rg.x = rvalid[node * 64 + r];
        rg.y = gidx[node * 64 + r];
    };

    auto LOADNODE = [&](NodeBuf& nb, int node, int2 rg) {
        nb.rv = rg.x;
        nb.gi = rg.y;
        if (rg.x != 0) {   // live row: load S-row slice + mask-row slice
            const float* srow = S + ((size_t)node * 64 + r) * 64 + g * 8;
            nb.sx[0] = *reinterpret_cast<const float4*>(srow);
            nb.sx[1] = *reinterpret_cast<const float4*>(srow + 4);
            nb.sx[2] = *reinterpret_cast<const float4*>(srow + 32);
            nb.sx[3] = *reinterpret_cast<const float4*>(srow + 36);
            const int* mrow = mask + ((size_t)node * 64 + r) * 64 + 4 * g;
#pragma unroll
            for (int tm = 0; tm < 4; ++tm)
                nb.mv[tm] = *reinterpret_cast<const int4*>(mrow + 16 * tm);
        } else {           // dead row: no memory requests; deterministic zeros
            float4 z4 = (float4){0.f, 0.f, 0.f, 0.f};
            int4   zi = (int4){0, 0, 0, 0};
#pragma unroll
            for (int q = 0; q < 4; ++q) { nb.sx[q] = z4; nb.mv[q] = zi; }
        }
    };

    auto COMPUTE = [&](const NodeBuf& nb, int node) {
        // ---- cvt S -> bf16 A-fragments ----
        bf16x8 af[2];
#pragma unroll
        for (int ks = 0; ks < 2; ++ks) {
            bf16x8 a;
            a[0] = (__bf16)nb.sx[2 * ks].x; a[1] = (__bf16)nb.sx[2 * ks].y;
            a[2] = (__bf16)nb.sx[2 * ks].z; a[3] = (__bf16)nb.sx[2 * ks].w;
            a[4] = (__bf16)nb.sx[2 * ks + 1].x; a[5] = (__bf16)nb.sx[2 * ks + 1].y;
            a[6] = (__bf16)nb.sx[2 * ks + 1].z; a[7] = (__bf16)nb.sx[2 * ks + 1].w;
            af[ks] = a;
        }

        // ---- fc1: h = relu(S @ W1 + b1); weights in regs, bias in acc-init ----
#pragma unroll
        for (int t = 0; t < 8; ++t) {
            f32x4 acc = (f32x4){b1v[t], b1v[t], b1v[t], b1v[t]};
            acc = __builtin_amdgcn_mfma_f32_16x16x32_bf16(af[0], w1f[t * 2 + 0], acc, 0, 0, 0);
            acc = __builtin_amdgcn_mfma_f32_16x16x32_bf16(af[1], w1f[t * 2 + 1], acc, 0, 0, 0);
#pragma unroll
            for (int j = 0; j < 4; ++j) {
                float v = acc[j] > 0.f ? acc[j] : 0.f;
                h_lds[w][4 * g + j][16 * t + lc] = (__bf16)v;   // h row=4g+j, col=16t+lc
            }
        }
        // per-wave tile: no barrier (compiler inserts lgkmcnt waits)

        // ---- fc2 SWAPPED: lacc[tm][j] = logits[r=16w+lc][c=16tm+4g+j]; weights in regs, b2 in init ----
        f32x4 lacc[4];
#pragma unroll
        for (int tm = 0; tm < 4; ++tm)
            lacc[tm] = (f32x4){b2v4[tm].x, b2v4[tm].y, b2v4[tm].z, b2v4[tm].w};
#pragma unroll
        for (int ks = 0; ks < 4; ++ks) {
            bf16x8 ah = *reinterpret_cast<const bf16x8*>(&h_lds[w][lc][ks * 32 + g * 8]);
#pragma unroll
            for (int tm = 0; tm < 4; ++tm)
                lacc[tm] = __builtin_amdgcn_mfma_f32_16x16x32_bf16(w2f[ks * 4 + tm], ah, lacc[tm], 0, 0, 0);
        }

        // ---- per-lane masked softmax + gather; dead rows (mv==0) fall through to mval=0 ----
        float l[4][4];
        float mt[4];
#pragma unroll
        for (int tm = 0; tm < 4; ++tm) {
            const int4 m4 = nb.mv[tm];
            l[tm][0] = m4.x ? lacc[tm][0] : -3.0e38f;
            l[tm][1] = m4.y ? lacc[tm][1] : -3.0e38f;
            l[tm][2] = m4.z ? lacc[tm][2] : -3.0e38f;
            l[tm][3] = m4.w ? lacc[tm][3] : -3.0e38f;
            mt[tm] = fmaxf(fmaxf(l[tm][0], l[tm][1]), fmaxf(l[tm][2], l[tm][3]));
        }
        float mx = fmaxf(fmaxf(mt[0], mt[1]), fmaxf(mt[2], mt[3]));
        mx = fmaxf(mx, __shfl_xor(mx, 16));
        mx = fmaxf(mx, __shfl_xor(mx, 32));

        float st[4];
#pragma unroll
        for (int tm = 0; tm < 4; ++tm) {
#pragma unroll
            for (int j = 0; j < 4; ++j) l[tm][j] = __expf(l[tm][j] - mx);  // masked -> exp(-huge) = 0
            st[tm] = (l[tm][0] + l[tm][1]) + (l[tm][2] + l[tm][3]);
        }
        float s = (st[0] + st[1]) + (st[2] + st[3]);
        s += __shfl_xor(s, 16);
        s += __shfl_xor(s, 32);

        const int gi = nb.gi;
        float sel = 0.f;
#pragma unroll
        for (int tm = 0; tm < 4; ++tm)
#pragma unroll
            for (int j = 0; j < 4; ++j)
                sel += (gi == (16 * tm + 4 * g + j)) ? l[tm][j] : 0.f;
        sel += __shfl_xor(sel, 16);
        sel += __shfl_xor(sel, 32);

        if (g == 0) {
            float mval = (nb.rv != 0 && s > 0.f) ? (sel / s) : 0.f;
            midg[(size_t)node * 64 + r] = mval;
        }
    };

    // ---- persistent loop: depth-1 A/B ping-pong on S/mask, rv/gi one iteration ahead ----
    int node = blockIdx.x;
    NodeBuf A, B;
    int2 rgA, rgB, rgT;
    rgT.x = 0; rgT.y = 0;
    LOADRV(rgA, node);
    if (node + NSLOT < NN) LOADRV(rgB, node + NSLOT); else { rgB.x = 0; rgB.y = 0; }
    LOADNODE(A, node, rgA);    // one-time rv wait in prologue
    for (;;) {
        int n1 = node + NSLOT;
        int n2 = node + 2 * NSLOT;
        if (n2 < NN) LOADRV(rgT, n2);        // rv/gi prefetch, consumed next phase
        if (n1 < NN) LOADNODE(B, n1, rgB);   // predicate arrived one iteration ago
        COMPUTE(A, node);
        if (n1 >= NN) break;
        node = n1;
        n1 = node + NSLOT;
        n2 = node + 2 * NSLOT;
        if (n2 < NN) LOADRV(rgB, n2);
        if (n1 < NN) LOADNODE(A, n1, rgT);
        COMPUTE(B, node);
        if (n1 >= NN) break;
        node = n1;
    }
}

// ---------------- Stage 2: out = sigmoid(relu(mid@W3+b3)@W4+b4) ----------------
__global__ __launch_bounds__(256) void vpsl_stage2(
    const float* __restrict__ midg, const float* __restrict__ W3,
    const float* __restrict__ b3, const float* __restrict__ W4,
    const float* __restrict__ b4, float* __restrict__ out)
{
    __shared__ float mid_lds[2][64];
    __shared__ float red[2][128];
    const int tid = threadIdx.x;
    const int b = blockIdx.x;          // nodes 2b, 2b+1
    if (tid < 128) mid_lds[tid >> 6][tid & 63] = midg[(size_t)b * 128 + tid];
    __syncthreads();
    const int half = tid >> 7;
    const int t = tid & 127;
    float acc = 0.f;
#pragma unroll 8
    for (int k = 0; k < 64; ++k) acc += mid_lds[half][k] * W3[k * 128 + t];
    acc += b3[t];
    acc = acc > 0.f ? acc : 0.f;
    red[half][t] = acc * W4[t];
    __syncthreads();
    if ((tid & 127) < 64) {            // waves 0 and 2
        const int h2 = tid >> 7;
        const int tt = tid & 63;
        float v = red[h2][tt] + red[h2][tt + 64];
#pragma unroll
        for (int off = 1; off < 64; off <<= 1) v += __shfl_xor(v, off);
        if (tt == 0) out[b * 2 + h2] = 1.f / (1.f + __expf(-(v + b4[0])));
    }
}

// ---------------- Fallback fused kernel (used only if ws_size is too small) ----------------
__global__ __launch_bounds__(256) void vpsl_fused(
    const float* __restrict__ S, const int* __restrict__ mask,
    const int* __restrict__ gidx, const int* __restrict__ rvalid,
    const __bf16* __restrict__ w1p, const __bf16* __restrict__ w2p,
    const float* __restrict__ b1, const float* __restrict__ b2,
    const float* __restrict__ W3, const float* __restrict__ b3,
    const float* __restrict__ W4, const float* __restrict__ b4,
    float* __restrict__ out)
{
    __shared__ __align__(16) __bf16 h_lds[4][16][136];
    __shared__ float mid_s[64];
    __shared__ int   gi_s[64];
    __shared__ int   rv_s[64];
    __shared__ float red_s[128];

    const int n    = blockIdx.x;
    const int tid  = threadIdx.x;
    const int w    = tid >> 6;
    const int lane = tid & 63;
    const int g    = lane >> 4;
    const int lc   = lane & 15;

    if (tid < 64) {
        gi_s[tid] = gidx[(size_t)n * 64 + tid];
        rv_s[tid] = rvalid[(size_t)n * 64 + tid];
    }
    float b1v[8];
#pragma unroll
    for (int t = 0; t < 8; ++t) b1v[t] = b1[t * 16 + lc];
    float b2v[4];
#pragma unroll
    for (int t = 0; t < 4; ++t) b2v[t] = b2[t * 16 + lc];

    const float* srow = S + ((size_t)n * 64 + 16 * w + lc) * 64;
    bf16x8 af[2];
#pragma unroll
    for (int ks = 0; ks < 2; ++ks) {
        const float4* p = reinterpret_cast<const float4*>(srow + ks * 32 + g * 8);
        float4 x0 = p[0], x1 = p[1];
        bf16x8 a;
        a[0] = (__bf16)x0.x; a[1] = (__bf16)x0.y; a[2] = (__bf16)x0.z; a[3] = (__bf16)x0.w;
        a[4] = (__bf16)x1.x; a[5] = (__bf16)x1.y; a[6] = (__bf16)x1.z; a[7] = (__bf16)x1.w;
        af[ks] = a;
    }
    f32x4 hacc[8];
#pragma unroll
    for (int t = 0; t < 8; ++t) hacc[t] = (f32x4){0.f, 0.f, 0.f, 0.f};
#pragma unroll
    for (int ks = 0; ks < 2; ++ks)
#pragma unroll
        for (int t = 0; t < 8; ++t) {
            bf16x8 bf = *reinterpret_cast<const bf16x8*>(w1p + (t * 16 + lc) * 64 + ks * 32 + g * 8);
            hacc[t] = __builtin_amdgcn_mfma_f32_16x16x32_bf16(af[ks], bf, hacc[t], 0, 0, 0);
        }
#pragma unroll
    for (int t = 0; t < 8; ++t)
#pragma unroll
        for (int j = 0; j < 4; ++j) {
            float v = hacc[t][j] + b1v[t];
            v = v > 0.f ? v : 0.f;
            h_lds[w][4 * g + j][16 * t + lc] = (__bf16)v;
        }
    __syncthreads();

    f32x4 lacc[4];
#pragma unroll
    for (int t = 0; t < 4; ++t) lacc[t] = (f32x4){0.f, 0.f, 0.f, 0.f};
#pragma unroll
    for (int ks = 0; ks < 4; ++ks) {
        bf16x8 ah = *reinterpret_cast<const bf16x8*>(&h_lds[w][lc][ks * 32 + g * 8]);
#pragma unroll
        for (int t = 0; t < 4; ++t) {
            bf16x8 bf = *reinterpret_cast<const bf16x8*>(w2p + (t * 16 + lc) * 128 + ks * 32 + g * 8);
            lacc[t] = __builtin_amdgcn_mfma_f32_16x16x32_bf16(ah, bf, lacc[t], 0, 0, 0);
        }
    }
#pragma unroll
    for (int j = 0; j < 4; ++j) {
        const int row = 16 * w + 4 * g + j;
        const int* mrow = mask + ((size_t)n * 64 + row) * 64 + lc;
        int m[4];
#pragma unroll
        for (int t = 0; t < 4; ++t) m[t] = mrow[16 * t];
        float l[4];
#pragma unroll
        for (int t = 0; t < 4; ++t) l[t] = m[t] ? (lacc[t][j] + b2v[t]) : -3.0e38f;
        float mx = fmaxf(fmaxf(l[0], l[1]), fmaxf(l[2], l[3]));
#pragma unroll
        for (int off = 1; off < 16; off <<= 1) mx = fmaxf(mx, __shfl_xor(mx, off));
        float e[4];
#pragma unroll
        for (int t = 0; t < 4; ++t) e[t] = m[t] ? __expf(l[t] - mx) : 0.f;
        float s = (e[0] + e[1]) + (e[2] + e[3]);
#pragma unroll
        for (int off = 1; off < 16; off <<= 1) s += __shfl_xor(s, off);
        const int gi = gi_s[row];
        float sel = 0.f;
#pragma unroll
        for (int t = 0; t < 4; ++t) sel += (((gi >> 4) == t) && ((gi & 15) == lc)) ? e[t] : 0.f;
#pragma unroll
        for (int off = 1; off < 16; off <<= 1) sel += __shfl_xor(sel, off);
        if (lc == 0) {
            float mval = (rv_s[row] != 0 && s > 0.f) ? (sel / s) : 0.f;
            mid_s[row] = mval;
        }
    }
    __syncthreads();

    if (tid < 128) {
        float acc = 0.f;
#pragma unroll 8
        for (int k = 0; k < 64; ++k) acc += mid_s[k] * W3[k * 128 + tid];
        acc += b3[tid];
        acc = acc > 0.f ? acc : 0.f;
        red_s[tid] = acc * W4[tid];
    }
    __syncthreads();
    if (tid < 64) {
        float v = red_s[tid] + red_s[tid + 64];
#pragma unroll
        for (int off = 1; off < 64; off <<= 1) v += __shfl_xor(v, off);
        if (tid == 0) out[n] = 1.f / (1.f + __expf(-(v + b4[0])));
    }
}

extern "C" void kernel_launch(void* const* d_in, const int* in_sizes, int n_in,
                              void* d_out, int out_size, void* d_ws, size_t ws_size,
                              hipStream_t stream) {
    const float* S    = (const float*)d_in[0];
    const int*   mask = (const int*)d_in[1];
    const int*   gidx = (const int*)d_in[2];
    const int*   rv   = (const int*)d_in[3];
    const float* W1   = (const float*)d_in[4];
    const float* b1   = (const float*)d_in[5];
    const float* W2   = (const float*)d_in[6];
    const float* b2   = (const float*)d_in[7];
    const float* W3   = (const float*)d_in[8];
    const float* b3   = (const float*)d_in[9];
    const float* W4   = (const float*)d_in[10];
    const float* b4   = (const float*)d_in[11];
    float* out = (float*)d_out;

    __bf16* w1p = (__bf16*)d_ws;              // 16 KB
    __bf16* w2p = w1p + 64 * 128;             // 16 KB
    float*  midg = (float*)(w2p + 64 * 128);  // 20000*64*4 = 5.12 MB

    const size_t need = 2 * 64 * 128 * sizeof(__bf16) + (size_t)NN * 64 * sizeof(float);

    hipLaunchKernelGGL(pack_w, dim3(32), dim3(256), 0, stream, W1, W2, w1p, w2p);
    if (ws_size >= need) {
        hipLaunchKernelGGL(vpsl_stage1p, dim3(GRID1), dim3(256), 0, stream,
                           S, mask, gidx, rv, w1p, w2p, b1, b2, midg);
        hipLaunchKernelGGL(vpsl_stage2, dim3(NN / 2), dim3(256), 0, stream,
                           midg, W3, b3, W4, b4, out);
    } else {
        hipLaunchKernelGGL(vpsl_fused, dim3(NN), dim3(256), 0, stream,
                           S, mask, gidx, rv, w1p, w2p, b1, b2, W3, b3, W4, b4, out);
    }
}

// Round 15
// 135.277 us; speedup vs baseline: 2.2712x; 2.2712x over previous
//
#include <hip/hip_runtime.h>
#include <hip/hip_bf16.h>

typedef __attribute__((ext_vector_type(8))) __bf16 bf16x8;
typedef __attribute__((ext_vector_type(4))) float f32x4;

#define NN 20000
#define GRID1 1024   // 256-thread blocks, 4 blocks/CU target (LDS ~36KB/block)
#define NSLOT 1024   // node stride = number of slots (1 slot per block)

// Pack W1 (64x128 f32, row-major) -> w1p[c][k] bf16 (c<128, k<64)
// Pack W2 (128x64 f32, row-major) -> w2p[c][k] bf16 (c<64, k<128)
__global__ void pack_w(const float* __restrict__ W1, const float* __restrict__ W2,
                       __bf16* __restrict__ w1p, __bf16* __restrict__ w2p) {
    int i = blockIdx.x * 256 + threadIdx.x;   // grid 32 * 256 = 8192
    if (i < 64 * 128) {
        int c = i >> 6, k = i & 63;
        w1p[i] = (__bf16)W1[k * 128 + c];
        int c2 = i >> 7, k2 = i & 127;
        w2p[i] = (__bf16)W2[k2 * 64 + c2];
    }
}

struct NodeBuf { float4 sx[4]; int4 mv[4]; int gi; int rv; };

// ---------------- Stage 1 (persistent, 256 threads = 4 waves = 1 node-slot) ----------------
// fc1 SWAPPED (mfma(W1,S) -> h^T fragments): lane holds 4 CONSECUTIVE h columns of its row
// -> one ds_write_b64 per t (8 wide writes/iter) instead of 32 scalar b16 scatter writes.
// h LDS layout unchanged -> fc2 ds_read_b128 unchanged. Bias b1 folded into MFMA C-init.
// rv-predicated loads + rv/gi one iteration ahead (R12/R13 pipeline).
__global__ __launch_bounds__(256, 4) void vpsl_stage1p(
    const float* __restrict__ S, const int* __restrict__ mask,
    const int* __restrict__ gidx, const int* __restrict__ rvalid,
    const __bf16* __restrict__ w1p, const __bf16* __restrict__ w2p,
    const float* __restrict__ b1, const float* __restrict__ b2,
    float* __restrict__ midg)
{
    __shared__ __align__(16) __bf16 w1_lds[128 * 64];    // [c<128][k<64], swizzled rows, 16 KB
    __shared__ __align__(16) __bf16 w2_lds[64 * 128];    // [c<64][k<128], swizzled rows, 16 KB
    __shared__ __align__(16) __bf16 h_lds[4][16][136];   // per-wave h tile [row r][col c], pitch 136

    const int tid  = threadIdx.x;
    const int w    = tid >> 6;     // wave 0..3 -> rows 16w..16w+15
    const int lane = tid & 63;
    const int g    = lane >> 4;    // 16-lane group
    const int lc   = lane & 15;
    const int swz  = (lc & 7) << 4;

    // ---- stage weights into LDS once (rows XOR-swizzled) ----
    for (int c = tid; c < 1024; c += 256) {
        int b = c * 16;
        int r1 = b >> 7, o1 = b & 127;
        *reinterpret_cast<float4*>(reinterpret_cast<char*>(w1_lds) + r1 * 128 + (o1 ^ ((r1 & 7) << 4)))
            = reinterpret_cast<const float4*>(w1p)[c];
        int r2 = b >> 8, o2 = b & 255;
        *reinterpret_cast<float4*>(reinterpret_cast<char*>(w2_lds) + r2 * 256 + (o2 ^ ((r2 & 7) << 4)))
            = reinterpret_cast<const float4*>(w2p)[c];
    }

    // biases: b1 indexed by c = 16t+4g+j (swapped fc1 output), b2 per-lane as before
    float4 b1v4[8];
#pragma unroll
    for (int t = 0; t < 8; ++t) b1v4[t] = *reinterpret_cast<const float4*>(b1 + 16 * t + 4 * g);
    float4 b2v4[4];
#pragma unroll
    for (int tm = 0; tm < 4; ++tm) b2v4[tm] = *reinterpret_cast<const float4*>(b2 + 16 * tm + 4 * g);

    __syncthreads();   // weights staged (only barrier in the kernel)

    const int r = 16 * w + lc;   // this lane's softmax row
    const char* wc1 = reinterpret_cast<const char*>(w1_lds);
    const char* wc2 = reinterpret_cast<const char*>(w2_lds);

    auto LOADRV = [&](int2& rg, int node) {
        rg.x = rvalid[node * 64 + r];
        rg.y = gidx[node * 64 + r];
    };

    auto LOADNODE = [&](NodeBuf& nb, int node, int2 rg) {
        nb.rv = rg.x;
        nb.gi = rg.y;
        if (rg.x != 0) {   // live row: load S-row slice + mask-row slice
            const float* srow = S + ((size_t)node * 64 + r) * 64 + g * 8;
            nb.sx[0] = *reinterpret_cast<const float4*>(srow);
            nb.sx[1] = *reinterpret_cast<const float4*>(srow + 4);
            nb.sx[2] = *reinterpret_cast<const float4*>(srow + 32);
            nb.sx[3] = *reinterpret_cast<const float4*>(srow + 36);
            const int* mrow = mask + ((size_t)node * 64 + r) * 64 + 4 * g;
#pragma unroll
            for (int tm = 0; tm < 4; ++tm)
                nb.mv[tm] = *reinterpret_cast<const int4*>(mrow + 16 * tm);
        } else {           // dead row: no memory requests; deterministic zeros
            float4 z4 = (float4){0.f, 0.f, 0.f, 0.f};
            int4   zi = (int4){0, 0, 0, 0};
#pragma unroll
            for (int q = 0; q < 4; ++q) { nb.sx[q] = z4; nb.mv[q] = zi; }
        }
    };

    auto COMPUTE = [&](const NodeBuf& nb, int node) {
        // ---- cvt S -> bf16 fragments (used as MFMA B-operand after the swap) ----
        bf16x8 af[2];
#pragma unroll
        for (int ks = 0; ks < 2; ++ks) {
            bf16x8 a;
            a[0] = (__bf16)nb.sx[2 * ks].x; a[1] = (__bf16)nb.sx[2 * ks].y;
            a[2] = (__bf16)nb.sx[2 * ks].z; a[3] = (__bf16)nb.sx[2 * ks].w;
            a[4] = (__bf16)nb.sx[2 * ks + 1].x; a[5] = (__bf16)nb.sx[2 * ks + 1].y;
            a[6] = (__bf16)nb.sx[2 * ks + 1].z; a[7] = (__bf16)nb.sx[2 * ks + 1].w;
            af[ks] = a;
        }

        // ---- fc1 SWAPPED: mfma(W1, S) -> lane holds h[row=lc][cols 16t+4g+0..3] ----
        // bias in C-init; relu+pack -> single ds_write_b64 per t
#pragma unroll
        for (int t = 0; t < 8; ++t) {
            f32x4 acc = (f32x4){b1v4[t].x, b1v4[t].y, b1v4[t].z, b1v4[t].w};
            bf16x8 bw0 = *reinterpret_cast<const bf16x8*>(
                wc1 + (t * 16 + lc) * 128 + ((0 * 64 + g * 16) ^ swz));
            acc = __builtin_amdgcn_mfma_f32_16x16x32_bf16(bw0, af[0], acc, 0, 0, 0);
            bf16x8 bw1 = *reinterpret_cast<const bf16x8*>(
                wc1 + (t * 16 + lc) * 128 + ((1 * 64 + g * 16) ^ swz));
            acc = __builtin_amdgcn_mfma_f32_16x16x32_bf16(bw1, af[1], acc, 0, 0, 0);
            union { __bf16 h4[4]; uint2 u2; } pk;
#pragma unroll
            for (int j = 0; j < 4; ++j) {
                float v = acc[j] > 0.f ? acc[j] : 0.f;
                pk.h4[j] = (__bf16)v;
            }
            *reinterpret_cast<uint2*>(&h_lds[w][lc][16 * t + 4 * g]) = pk.u2;   // 8B aligned, 2-way alias (free)
        }
        // per-wave tile: no barrier (compiler inserts lgkmcnt waits)

        // ---- fc2 SWAPPED: lacc[tm][j] = logits[r=16w+lc][c=16tm+4g+j]; b2 in C-init ----
        f32x4 lacc[4];
#pragma unroll
        for (int tm = 0; tm < 4; ++tm)
            lacc[tm] = (f32x4){b2v4[tm].x, b2v4[tm].y, b2v4[tm].z, b2v4[tm].w};
#pragma unroll
        for (int ks = 0; ks < 4; ++ks) {
            bf16x8 ah = *reinterpret_cast<const bf16x8*>(&h_lds[w][lc][ks * 32 + g * 8]);
#pragma unroll
            for (int tm = 0; tm < 4; ++tm) {
                bf16x8 bw = *reinterpret_cast<const bf16x8*>(
                    wc2 + (tm * 16 + lc) * 256 + ((ks * 64 + g * 16) ^ swz));
                lacc[tm] = __builtin_amdgcn_mfma_f32_16x16x32_bf16(bw, ah, lacc[tm], 0, 0, 0);
            }
        }

        // ---- per-lane masked softmax + gather; dead rows (mv==0) fall through to mval=0 ----
        float l[4][4];
        float mt[4];
#pragma unroll
        for (int tm = 0; tm < 4; ++tm) {
            const int4 m4 = nb.mv[tm];
            l[tm][0] = m4.x ? lacc[tm][0] : -3.0e38f;
            l[tm][1] = m4.y ? lacc[tm][1] : -3.0e38f;
            l[tm][2] = m4.z ? lacc[tm][2] : -3.0e38f;
            l[tm][3] = m4.w ? lacc[tm][3] : -3.0e38f;
            mt[tm] = fmaxf(fmaxf(l[tm][0], l[tm][1]), fmaxf(l[tm][2], l[tm][3]));
        }
        float mx = fmaxf(fmaxf(mt[0], mt[1]), fmaxf(mt[2], mt[3]));
        mx = fmaxf(mx, __shfl_xor(mx, 16));
        mx = fmaxf(mx, __shfl_xor(mx, 32));

        float st[4];
#pragma unroll
        for (int tm = 0; tm < 4; ++tm) {
#pragma unroll
            for (int j = 0; j < 4; ++j) l[tm][j] = __expf(l[tm][j] - mx);  // masked -> exp(-huge) = 0
            st[tm] = (l[tm][0] + l[tm][1]) + (l[tm][2] + l[tm][3]);
        }
        float s = (st[0] + st[1]) + (st[2] + st[3]);
        s += __shfl_xor(s, 16);
        s += __shfl_xor(s, 32);

        const int gi = nb.gi;
        float sel = 0.f;
#pragma unroll
        for (int tm = 0; tm < 4; ++tm)
#pragma unroll
            for (int j = 0; j < 4; ++j)
                sel += (gi == (16 * tm + 4 * g + j)) ? l[tm][j] : 0.f;
        sel += __shfl_xor(sel, 16);
        sel += __shfl_xor(sel, 32);

        if (g == 0) {
            float mval = (nb.rv != 0 && s > 0.f) ? (sel / s) : 0.f;
            midg[(size_t)node * 64 + r] = mval;
        }
    };

    // ---- persistent loop: depth-1 A/B ping-pong on S/mask, rv/gi one iteration ahead ----
    int node = blockIdx.x;
    NodeBuf A, B;
    int2 rgA, rgB, rgT;
    rgT.x = 0; rgT.y = 0;
    LOADRV(rgA, node);
    if (node + NSLOT < NN) LOADRV(rgB, node + NSLOT); else { rgB.x = 0; rgB.y = 0; }
    LOADNODE(A, node, rgA);    // one-time rv wait in prologue
    for (;;) {
        int n1 = node + NSLOT;
        int n2 = node + 2 * NSLOT;
        if (n2 < NN) LOADRV(rgT, n2);        // rv/gi prefetch, consumed next phase
        if (n1 < NN) LOADNODE(B, n1, rgB);   // predicate arrived one iteration ago
        COMPUTE(A, node);
        if (n1 >= NN) break;
        node = n1;
        n1 = node + NSLOT;
        n2 = node + 2 * NSLOT;
        if (n2 < NN) LOADRV(rgB, n2);
        if (n1 < NN) LOADNODE(A, n1, rgT);
        COMPUTE(B, node);
        if (n1 >= NN) break;
        node = n1;
    }
}

// ---------------- Stage 2: out = sigmoid(relu(mid@W3+b3)@W4+b4) ----------------
__global__ __launch_bounds__(256) void vpsl_stage2(
    const float* __restrict__ midg, const float* __restrict__ W3,
    const float* __restrict__ b3, const float* __restrict__ W4,
    const float* __restrict__ b4, float* __restrict__ out)
{
    __shared__ float mid_lds[2][64];
    __shared__ float red[2][128];
    const int tid = threadIdx.x;
    const int b = blockIdx.x;          // nodes 2b, 2b+1
    if (tid < 128) mid_lds[tid >> 6][tid & 63] = midg[(size_t)b * 128 + tid];
    __syncthreads();
    const int half = tid >> 7;
    const int t = tid & 127;
    float acc = 0.f;
#pragma unroll 8
    for (int k = 0; k < 64; ++k) acc += mid_lds[half][k] * W3[k * 128 + t];
    acc += b3[t];
    acc = acc > 0.f ? acc : 0.f;
    red[half][t] = acc * W4[t];
    __syncthreads();
    if ((tid & 127) < 64) {            // waves 0 and 2
        const int h2 = tid >> 7;
        const int tt = tid & 63;
        float v = red[h2][tt] + red[h2][tt + 64];
#pragma unroll
        for (int off = 1; off < 64; off <<= 1) v += __shfl_xor(v, off);
        if (tt == 0) out[b * 2 + h2] = 1.f / (1.f + __expf(-(v + b4[0])));
    }
}

// ---------------- Fallback fused kernel (used only if ws_size is too small) ----------------
__global__ __launch_bounds__(256) void vpsl_fused(
    const float* __restrict__ S, const int* __restrict__ mask,
    const int* __restrict__ gidx, const int* __restrict__ rvalid,
    const __bf16* __restrict__ w1p, const __bf16* __restrict__ w2p,
    const float* __restrict__ b1, const float* __restrict__ b2,
    const float* __restrict__ W3, const float* __restrict__ b3,
    const float* __restrict__ W4, const float* __restrict__ b4,
    float* __restrict__ out)
{
    __shared__ __align__(16) __bf16 h_lds[4][16][136];
    __shared__ float mid_s[64];
    __shared__ int   gi_s[64];
    __shared__ int   rv_s[64];
    __shared__ float red_s[128];

    const int n    = blockIdx.x;
    const int tid  = threadIdx.x;
    const int w    = tid >> 6;
    const int lane = tid & 63;
    const int g    = lane >> 4;
    const int lc   = lane & 15;

    if (tid < 64) {
        gi_s[tid] = gidx[(size_t)n * 64 + tid];
        rv_s[tid] = rvalid[(size_t)n * 64 + tid];
    }
    float b1v[8];
#pragma unroll
    for (int t = 0; t < 8; ++t) b1v[t] = b1[t * 16 + lc];
    float b2v[4];
#pragma unroll
    for (int t = 0; t < 4; ++t) b2v[t] = b2[t * 16 + lc];

    const float* srow = S + ((size_t)n * 64 + 16 * w + lc) * 64;
    bf16x8 af[2];
#pragma unroll
    for (int ks = 0; ks < 2; ++ks) {
        const float4* p = reinterpret_cast<const float4*>(srow + ks * 32 + g * 8);
        float4 x0 = p[0], x1 = p[1];
        bf16x8 a;
        a[0] = (__bf16)x0.x; a[1] = (__bf16)x0.y; a[2] = (__bf16)x0.z; a[3] = (__bf16)x0.w;
        a[4] = (__bf16)x1.x; a[5] = (__bf16)x1.y; a[6] = (__bf16)x1.z; a[7] = (__bf16)x1.w;
        af[ks] = a;
    }
    f32x4 hacc[8];
#pragma unroll
    for (int t = 0; t < 8; ++t) hacc[t] = (f32x4){0.f, 0.f, 0.f, 0.f};
#pragma unroll
    for (int ks = 0; ks < 2; ++ks)
#pragma unroll
        for (int t = 0; t < 8; ++t) {
            bf16x8 bf = *reinterpret_cast<const bf16x8*>(w1p + (t * 16 + lc) * 64 + ks * 32 + g * 8);
            hacc[t] = __builtin_amdgcn_mfma_f32_16x16x32_bf16(af[ks], bf, hacc[t], 0, 0, 0);
        }
#pragma unroll
    for (int t = 0; t < 8; ++t)
#pragma unroll
        for (int j = 0; j < 4; ++j) {
            float v = hacc[t][j] + b1v[t];
            v = v > 0.f ? v : 0.f;
            h_lds[w][4 * g + j][16 * t + lc] = (__bf16)v;
        }
    __syncthreads();

    f32x4 lacc[4];
#pragma unroll
    for (int t = 0; t < 4; ++t) lacc[t] = (f32x4){0.f, 0.f, 0.f, 0.f};
#pragma unroll
    for (int ks = 0; ks < 4; ++ks) {
        bf16x8 ah = *reinterpret_cast<const bf16x8*>(&h_lds[w][lc][ks * 32 + g * 8]);
#pragma unroll
        for (int t = 0; t < 4; ++t) {
            bf16x8 bf = *reinterpret_cast<const bf16x8*>(w2p + (t * 16 + lc) * 128 + ks * 32 + g * 8);
            lacc[t] = __builtin_amdgcn_mfma_f32_16x16x32_bf16(ah, bf, lacc[t], 0, 0, 0);
        }
    }
#pragma unroll
    for (int j = 0; j < 4; ++j) {
        const int row = 16 * w + 4 * g + j;
        const int* mrow = mask + ((size_t)n * 64 + row) * 64 + lc;
        int m[4];
#pragma unroll
        for (int t = 0; t < 4; ++t) m[t] = mrow[16 * t];
        float l[4];
#pragma unroll
        for (int t = 0; t < 4; ++t) l[t] = m[t] ? (lacc[t][j] + b2v[t]) : -3.0e38f;
        float mx = fmaxf(fmaxf(l[0], l[1]), fmaxf(l[2], l[3]));
#pragma unroll
        for (int off = 1; off < 16; off <<= 1) mx = fmaxf(mx, __shfl_xor(mx, off));
        float e[4];
#pragma unroll
        for (int t = 0; t < 4; ++t) e[t] = m[t] ? __expf(l[t] - mx) : 0.f;
        float s = (e[0] + e[1]) + (e[2] + e[3]);
#pragma unroll
        for (int off = 1; off < 16; off <<= 1) s += __shfl_xor(s, off);
        const int gi = gi_s[row];
        float sel = 0.f;
#pragma unroll
        for (int t = 0; t < 4; ++t) sel += (((gi >> 4) == t) && ((gi & 15) == lc)) ? e[t] : 0.f;
#pragma unroll
        for (int off = 1; off < 16; off <<= 1) sel += __shfl_xor(sel, off);
        if (lc == 0) {
            float mval = (rv_s[row] != 0 && s > 0.f) ? (sel / s) : 0.f;
            mid_s[row] = mval;
        }
    }
    __syncthreads();

    if (tid < 128) {
        float acc = 0.f;
#pragma unroll 8
        for (int k = 0; k < 64; ++k) acc += mid_s[k] * W3[k * 128 + tid];
        acc += b3[tid];
        acc = acc > 0.f ? acc : 0.f;
        red_s[tid] = acc * W4[tid];
    }
    __syncthreads();
    if (tid < 64) {
        float v = red_s[tid] + red_s[tid + 64];
#pragma unroll
        for (int off = 1; off < 64; off <<= 1) v += __shfl_xor(v, off);
        if (tid == 0) out[n] = 1.f / (1.f + __expf(-(v + b4[0])));
    }
}

extern "C" void kernel_launch(void* const* d_in, const int* in_sizes, int n_in,
                              void* d_out, int out_size, void* d_ws, size_t ws_size,
                              hipStream_t stream) {
    const float* S    = (const float*)d_in[0];
    const int*   mask = (const int*)d_in[1];
    const int*   gidx = (const int*)d_in[2];
    const int*   rv   = (const int*)d_in[3];
    const float* W1   = (const float*)d_in[4];
    const float* b1   = (const float*)d_in[5];
    const float* W2   = (const float*)d_in[6];
    const float* b2   = (const float*)d_in[7];
    const float* W3   = (const float*)d_in[8];
    const float* b3   = (const float*)d_in[9];
    const float* W4   = (const float*)d_in[10];
    const float* b4   = (const float*)d_in[11];
    float* out = (float*)d_out;

    __bf16* w1p = (__bf16*)d_ws;              // 16 KB
    __bf16* w2p = w1p + 64 * 128;             // 16 KB
    float*  midg = (float*)(w2p + 64 * 128);  // 20000*64*4 = 5.12 MB

    const size_t need = 2 * 64 * 128 * sizeof(__bf16) + (size_t)NN * 64 * sizeof(float);

    hipLaunchKernelGGL(pack_w, dim3(32), dim3(256), 0, stream, W1, W2, w1p, w2p);
    if (ws_size >= need) {
        hipLaunchKernelGGL(vpsl_stage1p, dim3(GRID1), dim3(256), 0, stream,
                           S, mask, gidx, rv, w1p, w2p, b1, b2, midg);
        hipLaunchKernelGGL(vpsl_stage2, dim3(NN / 2), dim3(256), 0, stream,
                           midg, W3, b3, W4, b4, out);
    } else {
        hipLaunchKernelGGL(vpsl_fused, dim3(NN), dim3(256), 0, stream,
                           S, mask, gidx, rv, w1p, w2p, b1, b2, W3, b3, W4, b4, out);
    }
}